// Round 6
// baseline (258.990 us; speedup 1.0000x reference)
//
#include <hip/hip_runtime.h>

#define NEG_SLOPE 0.2f

static constexpr int Hh   = 4;
static constexpr int Nn   = 50000;
static constexpr int Ee   = 1600000;
static constexpr int D    = 32;

static constexpr int GBITS = 7;                       // 128 nodes per bin
static constexpr int GW    = 1 << GBITS;
static constexpr int BPH   = 392;                     // 391 used + 1 pad (keeps NBIN % 8 == 0)
static constexpr int NBIN  = Hh * BPH;                // 1568 bins
static constexpr int CAP   = 4864;                    // mean 4096 + 12 sigma
static constexpr int S2CAP = CAP + GW;                // + <=1 pad slot per row
static constexpr int EPT2  = (CAP + 511) / 512;       // 10 staged edges/thread (pass 2)
static constexpr int T1    = 8192;                    // partition tile (edges)
static constexpr int TPB1  = 512;
static constexpr int EPT   = T1 / TPB1;               // 16 edges/thread
static constexpr int NPT   = (Ee + T1 - 1) / T1;      // 196 tiles/head
static constexpr int NPB   = NPT * Hh;                // 784 partition blocks
static constexpr int NG64  = (Nn + 63) / 64;          // 782 64-node groups/head
static constexpr int TPART = 250;                     // transform parts/head
static constexpr int NTB   = Hh * TPART;              // 1000 transform blocks

typedef _Float16 v2h __attribute__((ext_vector_type(2)));
struct H8 { v2h a, b, c, d; };                        // 8 halves = 16 B
union U16B { uint4 u; H8 h; };

#if defined(__has_builtin)
#if __has_builtin(__builtin_amdgcn_fdot2)
#define HAS_FDOT2 1
#endif
#endif

// ---------------------------------------------------------------------------
// Pass 1: two roles in one launch (block-uniform branch).
//   blocks [0, NPB)        : LDS-staged radix partition of edges into 1568
//                            bins (R2 structure; direct global scatter (R3)
//                            caused L2 write-allocate amplification).
//   blocks [NPB, NPB+NTB)  : xl/xr = x @ W_{l,r} per head, stored f16.
//                            W column in registers (R5: was ~76us of LDS
//                            W re-reads; compiler does not hoist).
// ---------------------------------------------------------------------------
union SMem {
    struct {
        unsigned stage[T1];          // 32 KB
        int lcur[BPH];
        int lstart[BPH];
        int gdst[BPH];
        int hs[512];
    } p;
    struct {
        float xs[64 * D];            // 64 nodes x 32 floats (8 KB)
    } t;
};

__global__ __launch_bounds__(TPB1, 4)
void pass1_kernel(const float* __restrict__ x, const float* __restrict__ Wl,
                  const float* __restrict__ Wr, const int* __restrict__ ei,
                  _Float16* __restrict__ xlh, _Float16* __restrict__ xrh,
                  int* __restrict__ bincur, unsigned* __restrict__ seg1) {
    __shared__ SMem sm;
    const int L   = blockIdx.x;
    const int tid = threadIdx.x;

    if (L < NPB) {
        // ------------------- partition role -------------------
        const int h  = L & 3;
        const int tb = (L >> 2) * T1;

        for (int i = tid; i < BPH; i += TPB1) sm.p.lcur[i] = 0;
        __syncthreads();

        const int4* srcp = (const int4*)(ei + (size_t)h * 2 * Ee);
        const int4* dstp = (const int4*)(ei + (size_t)h * 2 * Ee + Ee);

        unsigned ent[EPT];
        unsigned short rk[EPT];
#pragma unroll
        for (int k = 0; k < EPT / 4; ++k) {
            const int e4 = tb + 4 * (k * TPB1 + tid);    // Ee % 4 == 0
            if (e4 < Ee) {
                const int4 s4 = srcp[e4 >> 2];
                const int4 d4 = dstp[e4 >> 2];
                ent[4 * k + 0] = ((unsigned)s4.x << 16) | (unsigned)d4.x;
                ent[4 * k + 1] = ((unsigned)s4.y << 16) | (unsigned)d4.y;
                ent[4 * k + 2] = ((unsigned)s4.z << 16) | (unsigned)d4.z;
                ent[4 * k + 3] = ((unsigned)s4.w << 16) | (unsigned)d4.w;
                rk[4 * k + 0] = (unsigned short)atomicAdd(&sm.p.lcur[d4.x >> GBITS], 1);
                rk[4 * k + 1] = (unsigned short)atomicAdd(&sm.p.lcur[d4.y >> GBITS], 1);
                rk[4 * k + 2] = (unsigned short)atomicAdd(&sm.p.lcur[d4.z >> GBITS], 1);
                rk[4 * k + 3] = (unsigned short)atomicAdd(&sm.p.lcur[d4.w >> GBITS], 1);
            } else {
                ent[4*k+0] = ent[4*k+1] = ent[4*k+2] = ent[4*k+3] = 0xffffffffu;
            }
        }
        __syncthreads();

        // inclusive H-S scan of 392 counts (all 512 threads)
        sm.p.hs[tid] = (tid < BPH) ? sm.p.lcur[tid] : 0;
        __syncthreads();
        for (int o = 1; o < 512; o <<= 1) {
            int v = 0;
            if (tid >= o) v = sm.p.hs[tid - o];
            __syncthreads();
            sm.p.hs[tid] += v;
            __syncthreads();
        }
        if (tid < BPH) {
            sm.p.lstart[tid] = sm.p.hs[tid] - sm.p.lcur[tid];
            if (sm.p.lcur[tid] > 0) {
                const int g = atomicAdd(&bincur[h * BPH + tid], sm.p.lcur[tid]);
                sm.p.gdst[tid] = (h * BPH + tid) * CAP + g;
            }
        }
        __syncthreads();

        // reorder into LDS stage via saved rank
#pragma unroll
        for (int k = 0; k < EPT; ++k) {
            if (ent[k] != 0xffffffffu) {
                const int b = (int)((ent[k] & 0xffffu) >> GBITS);
                sm.p.stage[sm.p.lstart[b] + (int)rk[k]] = ent[k];
            }
        }
        __syncthreads();

        const int tot = sm.p.lstart[BPH - 1] + sm.p.lcur[BPH - 1];
        for (int i = tid; i < tot; i += TPB1) {
            const unsigned e = sm.p.stage[i];
            const int b = (int)((e & 0xffffu) >> GBITS);
            seg1[(size_t)sm.p.gdst[b] + (i - sm.p.lstart[b])] = e;
        }
    } else {
        // ------------------- transform role (persistent, W-in-regs) --------
        const int t    = L - NPB;
        const int h    = t & 3;
        const int part = t >> 2;             // 0..TPART-1
        const int c    = tid & 31;
        const int ng   = tid >> 5;           // 0..15 node sub-group

        // W column -> 64 VGPRs, once per block (coalesced per-k dword loads)
        float wlc[D], wrc[D];
#pragma unroll
        for (int k = 0; k < D; ++k) {
            wlc[k] = Wl[h * D * D + k * D + c];
            wrc[k] = Wr[h * D * D + k * D + c];
        }

        for (int nb = part; nb < NG64; nb += TPART) {
            __syncthreads();     // prior iteration's readers done
            const int base = nb * 64;
            const int nn   = (Nn - base) < 64 ? (Nn - base) : 64;
            const float4* xsrc = (const float4*)(x + ((size_t)h * Nn + base) * D);
            for (int i = tid; i < nn * 8; i += TPB1)
                ((float4*)sm.t.xs)[i] = xsrc[i];
            __syncthreads();

#pragma unroll
            for (int i = 0; i < 4; ++i) {
                const int nl = ng * 4 + i;       // local node 0..63
                if (nl < nn) {
                    const float4* xr4 = (const float4*)(sm.t.xs + nl * D);
                    float al = 0.f, ar = 0.f;
#pragma unroll
                    for (int kc = 0; kc < 8; ++kc) {
                        const float4 xv = xr4[kc];   // broadcast b128
                        al = fmaf(xv.x, wlc[4*kc+0], al); ar = fmaf(xv.x, wrc[4*kc+0], ar);
                        al = fmaf(xv.y, wlc[4*kc+1], al); ar = fmaf(xv.y, wrc[4*kc+1], ar);
                        al = fmaf(xv.z, wlc[4*kc+2], al); ar = fmaf(xv.z, wrc[4*kc+2], ar);
                        al = fmaf(xv.w, wlc[4*kc+3], al); ar = fmaf(xv.w, wrc[4*kc+3], ar);
                    }
                    const size_t o = ((size_t)h * Nn + base + nl) * D + c;
                    xlh[o] = (_Float16)al;
                    xrh[o] = (_Float16)ar;
                }
            }
        }
    }
}

// ---------------------------------------------------------------------------
// Pass 2 (fused rowsort + accum): one block per bin (128 nodes), 512 threads.
// Phase A : SINGLE-PASS seg1: each thread stages its <=10 edges in registers
//           (fully-unrolled, compile-time indices) during the histogram,
//           then scatters from registers -- deletes the 26MB global re-read.
//           Row runs padded to EVEN length: each 2-edge batch's indices are
//           one aligned ushort2 LDS broadcast read.
// Phase A': counting-sort row ids by DESCENDING degree (rowdeg[]) -> wave's
//           16 lockstep groups hold near-equal-degree rows.
// Phase B : 3-DEEP gather pipeline (A/B/C rotation + prefetched odd-edge D):
//           two proc-pairs (~240cy VALU) now cover the ~200cy L2 gather
//           latency; 2-deep only covered ~120cy (VALUBusy was 51%).
//           Proc order per row unchanged -> numerics identical.
// ---------------------------------------------------------------------------
__global__ __launch_bounds__(512, 8)
void sortaccum_kernel(const int* __restrict__ bincur, const unsigned* __restrict__ seg1,
                      const _Float16* __restrict__ xlh, const _Float16* __restrict__ xrh,
                      const float* __restrict__ att, const float* __restrict__ bias,
                      float* __restrict__ out) {
    __shared__ int rcnt[GW];
    __shared__ int rcur[GW];
    __shared__ int rowbeg[GW];
    __shared__ int rowdeg[GW];
    __shared__ unsigned short s2[S2CAP];
    __shared__ unsigned short order[GW];

    const int tid = threadIdx.x;
    const int L   = blockIdx.x;                 // 1568 = 196 * 8
    const int xcd = L & 7;
    const int h   = xcd >> 1;
    const int b   = ((L >> 3) << 1) | (L & 1);  // 0..391
    const int nodebase = b * GW;
    if (nodebase >= Nn) return;                 // pad bin (b==391), block-uniform
    const int bin = h * BPH + b;
    const int nrows = (Nn - nodebase) < GW ? (Nn - nodebase) : GW;
    const int cnt   = bincur[bin];
    const size_t base = (size_t)bin * CAP;
    const int hbase = h * Nn;

    if (tid < GW) rcnt[tid] = 0;
    __syncthreads();

    // single pass over seg1: stage in registers + histogram
    unsigned ev[EPT2];
#pragma unroll
    for (int k = 0; k < EPT2; ++k) {
        const int i = tid + k * 512;
        if (i < cnt) {
            ev[k] = seg1[base + i];
            atomicAdd(&rcnt[ev[k] & (GW - 1)], 1);
        }
    }
    __syncthreads();

    // extract degree, pad runs to even length, H-S scan the padded counts
    int deg = 0, pad = 0;
    if (tid < GW) {
        deg = rcnt[tid];
        rowdeg[tid] = deg;
        pad = (deg + 1) & ~1;
        rcnt[tid] = pad;
    }
    __syncthreads();
    for (int o = 1; o < GW; o <<= 1) {
        int a = 0;
        if (tid < GW && tid >= o) a = rcnt[tid - o];
        __syncthreads();
        if (tid < GW) rcnt[tid] += a;
        __syncthreads();
    }
    if (tid < GW) {
        const int excl = rcnt[tid] - pad;       // even (scan of evens)
        rcur[tid]   = excl;
        rowbeg[tid] = excl;
    }
    __syncthreads();

    // scatter from registers (no second seg1 read)
#pragma unroll
    for (int k = 0; k < EPT2; ++k) {
        const int i = tid + k * 512;
        if (i < cnt) {
            const int p = atomicAdd(&rcur[ev[k] & (GW - 1)], 1);
            s2[p] = (unsigned short)(ev[k] >> 16);
        }
    }
    __syncthreads();

    // ---------- phase A': counting-sort rows by descending degree ----------
    if (tid < GW) rcnt[tid] = 0;
    __syncthreads();
    int key = 0;
    if (tid < nrows) {
        key = deg > (GW - 1) ? 0 : (GW - 1 - deg);  // big degrees first
        atomicAdd(&rcnt[key], 1);
    }
    __syncthreads();
    int kv = 0;
    if (tid < GW) kv = rcnt[tid];
    for (int o = 1; o < GW; o <<= 1) {
        int a = 0;
        if (tid < GW && tid >= o) a = rcnt[tid - o];
        __syncthreads();
        if (tid < GW) rcnt[tid] += a;
        __syncthreads();
    }
    if (tid < GW) rcur[tid] = rcnt[tid] - kv;       // exclusive starts
    __syncthreads();
    if (tid < nrows) {
        const int p = atomicAdd(&rcur[key], 1);
        order[p] = (unsigned short)tid;
    }
    __syncthreads();

    // ------------------- phase B: accumulate -------------------
    const int l4  = tid & 3;
    const int gid = tid >> 2;                   // 128 groups

    v2h a0, a1, a2, a3;
    {
        const float* ap = att + h * D + l4 * 8;
        a0[0] = (_Float16)ap[0]; a0[1] = (_Float16)ap[1];
        a1[0] = (_Float16)ap[2]; a1[1] = (_Float16)ap[3];
        a2[0] = (_Float16)ap[4]; a2[1] = (_Float16)ap[5];
        a3[0] = (_Float16)ap[6]; a3[1] = (_Float16)ap[7];
    }
    const v2h sl2 = {(_Float16)NEG_SLOPE, (_Float16)NEG_SLOPE};
    const float* bp = bias + h * D + l4 * 8;
    const _Float16* xlb = xlh + (size_t)hbase * D + l4 * 8;

    for (int q = gid; q < nrows; q += 128) {
        const int j = (int)order[q];

        const int n = nodebase + j;
        const int r = hbase + n;
        const int beg = rowbeg[j];
        const int dg  = rowdeg[j];
        const int nb  = dg >> 1;                // 2-edge batches

        U16B xr8; xr8.u = *(const uint4*)(xrh + (size_t)r * D + l4 * 8);

        float ac0 = 0.f, ac1 = 0.f, ac2 = 0.f, ac3 = 0.f;
        float ac4 = 0.f, ac5 = 0.f, ac6 = 0.f, ac7 = 0.f;
        float den = 0.f;

        auto proc = [&](const H8& xg) {
            const v2h h0 = xg.a + xr8.h.a, h1 = xg.b + xr8.h.b;
            const v2h h2 = xg.c + xr8.h.c, h3 = xg.d + xr8.h.d;
            const v2h l0 = __builtin_elementwise_max(h0, h0 * sl2);
            const v2h l1 = __builtin_elementwise_max(h1, h1 * sl2);
            const v2h l2 = __builtin_elementwise_max(h2, h2 * sl2);
            const v2h l3 = __builtin_elementwise_max(h3, h3 * sl2);
            float p;
#ifdef HAS_FDOT2
            p = __builtin_amdgcn_fdot2(l0, a0, 0.f, false);
            p = __builtin_amdgcn_fdot2(l1, a1, p, false);
            p = __builtin_amdgcn_fdot2(l2, a2, p, false);
            p = __builtin_amdgcn_fdot2(l3, a3, p, false);
#else
            p  = (float)l0[0] * (float)a0[0] + (float)l0[1] * (float)a0[1];
            p += (float)l1[0] * (float)a1[0] + (float)l1[1] * (float)a1[1];
            p += (float)l2[0] * (float)a2[0] + (float)l2[1] * (float)a2[1];
            p += (float)l3[0] * (float)a3[0] + (float)l3[1] * (float)a3[1];
#endif
            p += __shfl_xor(p, 1, 4);
            p += __shfl_xor(p, 2, 4);
            const float w = __expf(p);
            ac0 = fmaf(w, (float)xg.a[0], ac0);
            ac1 = fmaf(w, (float)xg.a[1], ac1);
            ac2 = fmaf(w, (float)xg.b[0], ac2);
            ac3 = fmaf(w, (float)xg.b[1], ac3);
            ac4 = fmaf(w, (float)xg.c[0], ac4);
            ac5 = fmaf(w, (float)xg.c[1], ac5);
            ac6 = fmaf(w, (float)xg.d[0], ac6);
            ac7 = fmaf(w, (float)xg.d[1], ac7);
            den += w;
        };

        // prologue: batches 0,1 and the odd edge prefetched; self-loop proc
        // hides their latency.
        U16B gA0, gA1, gB0, gB1, gC0, gC1, gD0;
        if (nb > 0) {
            const ushort2 v = *(const ushort2*)(s2 + beg);
            gA0.u = *(const uint4*)(xlb + (size_t)v.x * D);
            gA1.u = *(const uint4*)(xlb + (size_t)v.y * D);
        }
        if (nb > 1) {
            const ushort2 v = *(const ushort2*)(s2 + beg + 2);
            gB0.u = *(const uint4*)(xlb + (size_t)v.x * D);
            gB1.u = *(const uint4*)(xlb + (size_t)v.y * D);
        }
        if (dg & 1) {
            const int s = (int)s2[beg + dg - 1];
            gD0.u = *(const uint4*)(xlb + (size_t)s * D);
        }
        {
            U16B xs; xs.u = *(const uint4*)(xlh + (size_t)r * D + l4 * 8);
            proc(xs.h);
        }

        // steady state: rotate A->B->C; always 2 batches of proc between a
        // fetch and its consumption.
        int k = 0;
        for (; k + 3 <= nb; k += 3) {
            {
                const ushort2 v = *(const ushort2*)(s2 + beg + 2 * (k + 2));
                gC0.u = *(const uint4*)(xlb + (size_t)v.x * D);
                gC1.u = *(const uint4*)(xlb + (size_t)v.y * D);
            }
            proc(gA0.h);
            proc(gA1.h);
            if (k + 3 < nb) {
                const ushort2 v = *(const ushort2*)(s2 + beg + 2 * (k + 3));
                gA0.u = *(const uint4*)(xlb + (size_t)v.x * D);
                gA1.u = *(const uint4*)(xlb + (size_t)v.y * D);
            }
            proc(gB0.h);
            proc(gB1.h);
            if (k + 4 < nb) {
                const ushort2 v = *(const ushort2*)(s2 + beg + 2 * (k + 4));
                gB0.u = *(const uint4*)(xlb + (size_t)v.x * D);
                gB1.u = *(const uint4*)(xlb + (size_t)v.y * D);
            }
            proc(gC0.h);
            proc(gC1.h);
        }
        const int rem = nb - k;                 // 0, 1, or 2
        if (rem >= 1) { proc(gA0.h); proc(gA1.h); }
        if (rem >= 2) { proc(gB0.h); proc(gB1.h); }
        if (dg & 1)   { proc(gD0.h); }

        const float inv = 1.f / den;
        float* op = out + (size_t)n * (Hh * D) + h * D + l4 * 8;
        float4 o0, o1;
        o0.x = ac0 * inv + bp[0]; o0.y = ac1 * inv + bp[1];
        o0.z = ac2 * inv + bp[2]; o0.w = ac3 * inv + bp[3];
        o1.x = ac4 * inv + bp[4]; o1.y = ac5 * inv + bp[5];
        o1.z = ac6 * inv + bp[6]; o1.w = ac7 * inv + bp[7];
        ((float4*)op)[0] = o0;
        ((float4*)op)[1] = o1;
    }
}

extern "C" void kernel_launch(void* const* d_in, const int* in_sizes, int n_in,
                              void* d_out, int out_size, void* d_ws, size_t ws_size,
                              hipStream_t stream) {
    const float* x    = (const float*)d_in[0];
    const int*   ei   = (const int*)d_in[1];
    const float* Wl   = (const float*)d_in[2];
    const float* Wr   = (const float*)d_in[3];
    const float* att  = (const float*)d_in[4];
    const float* bias = (const float*)d_in[5];
    float* out = (float*)d_out;

    // workspace: xlh[6.4M f16] | xrh[6.4M f16] | seg1[1568*4864 u32 = 30.5MB] | bincur[1568]
    _Float16* xlh  = (_Float16*)d_ws;
    _Float16* xrh  = xlh + (size_t)Hh * Nn * D;
    unsigned* seg1 = (unsigned*)(xrh + (size_t)Hh * Nn * D);
    int*      bincur = (int*)(seg1 + (size_t)NBIN * CAP);

    hipMemsetAsync(bincur, 0, NBIN * sizeof(int), stream);

    pass1_kernel<<<NPB + NTB, TPB1, 0, stream>>>(x, Wl, Wr, ei, xlh, xrh, bincur, seg1);

    sortaccum_kernel<<<NBIN, 512, 0, stream>>>(bincur, seg1, xlh, xrh, att, bias, out);
}

// Round 7
// 204.255 us; speedup vs baseline: 1.2680x; 1.2680x over previous
//
#include <hip/hip_runtime.h>

#define NEG_SLOPE 0.2f

static constexpr int Hh   = 4;
static constexpr int Nn   = 50000;
static constexpr int Ee   = 1600000;
static constexpr int D    = 32;

static constexpr int GBITS = 7;                       // 128 nodes per bin
static constexpr int GW    = 1 << GBITS;
static constexpr int BPH   = 392;                     // 391 used + 1 pad (keeps NBIN % 8 == 0)
static constexpr int NBIN  = Hh * BPH;                // 1568 bins
static constexpr int CAP   = 4864;                    // mean 4096 + 12 sigma
static constexpr int S2CAP = CAP + GW;                // + <=1 pad slot per row
static constexpr int EPT2  = (CAP + 511) / 512;       // 10 staged edges/thread (pass 2)
static constexpr int T1    = 8192;                    // partition tile (edges)
static constexpr int TPB1  = 512;
static constexpr int EPT   = T1 / TPB1;               // 16 edges/thread
static constexpr int NPT   = (Ee + T1 - 1) / T1;      // 196 tiles/head
static constexpr int NPB   = NPT * Hh;                // 784 partition blocks
static constexpr int NG64  = (Nn + 63) / 64;          // 782 64-node groups/head
static constexpr int TPART = 250;                     // transform parts/head
static constexpr int NTB   = Hh * TPART;              // 1000 transform blocks

typedef _Float16 v2h __attribute__((ext_vector_type(2)));
struct H8 { v2h a, b, c, d; };                        // 8 halves = 16 B
union U16B { uint4 u; H8 h; };

#if defined(__has_builtin)
#if __has_builtin(__builtin_amdgcn_fdot2)
#define HAS_FDOT2 1
#endif
#endif

// ---------------------------------------------------------------------------
// Pass 1: two roles in one launch (block-uniform branch).
//   blocks [0, NPB)        : LDS-staged radix partition of edges into 1568
//                            bins (R2 structure; direct global scatter (R3)
//                            caused L2 write-allocate amplification).
//   blocks [NPB, NPB+NTB)  : xl/xr = x @ W_{l,r} per head, stored f16.
//                            W column in registers (R5: was ~76us of LDS
//                            W re-reads; compiler does not hoist).
// ---------------------------------------------------------------------------
union SMem {
    struct {
        unsigned stage[T1];          // 32 KB
        int lcur[BPH];
        int lstart[BPH];
        int gdst[BPH];
        int hs[512];
    } p;
    struct {
        float xs[64 * D];            // 64 nodes x 32 floats (8 KB)
    } t;
};

__global__ __launch_bounds__(TPB1, 4)
void pass1_kernel(const float* __restrict__ x, const float* __restrict__ Wl,
                  const float* __restrict__ Wr, const int* __restrict__ ei,
                  _Float16* __restrict__ xlh, _Float16* __restrict__ xrh,
                  int* __restrict__ bincur, unsigned* __restrict__ seg1) {
    __shared__ SMem sm;
    const int L   = blockIdx.x;
    const int tid = threadIdx.x;

    if (L < NPB) {
        // ------------------- partition role -------------------
        const int h  = L & 3;
        const int tb = (L >> 2) * T1;

        for (int i = tid; i < BPH; i += TPB1) sm.p.lcur[i] = 0;
        __syncthreads();

        const int4* srcp = (const int4*)(ei + (size_t)h * 2 * Ee);
        const int4* dstp = (const int4*)(ei + (size_t)h * 2 * Ee + Ee);

        unsigned ent[EPT];
        unsigned short rk[EPT];
#pragma unroll
        for (int k = 0; k < EPT / 4; ++k) {
            const int e4 = tb + 4 * (k * TPB1 + tid);    // Ee % 4 == 0
            if (e4 < Ee) {
                const int4 s4 = srcp[e4 >> 2];
                const int4 d4 = dstp[e4 >> 2];
                ent[4 * k + 0] = ((unsigned)s4.x << 16) | (unsigned)d4.x;
                ent[4 * k + 1] = ((unsigned)s4.y << 16) | (unsigned)d4.y;
                ent[4 * k + 2] = ((unsigned)s4.z << 16) | (unsigned)d4.z;
                ent[4 * k + 3] = ((unsigned)s4.w << 16) | (unsigned)d4.w;
                rk[4 * k + 0] = (unsigned short)atomicAdd(&sm.p.lcur[d4.x >> GBITS], 1);
                rk[4 * k + 1] = (unsigned short)atomicAdd(&sm.p.lcur[d4.y >> GBITS], 1);
                rk[4 * k + 2] = (unsigned short)atomicAdd(&sm.p.lcur[d4.z >> GBITS], 1);
                rk[4 * k + 3] = (unsigned short)atomicAdd(&sm.p.lcur[d4.w >> GBITS], 1);
            } else {
                ent[4*k+0] = ent[4*k+1] = ent[4*k+2] = ent[4*k+3] = 0xffffffffu;
            }
        }
        __syncthreads();

        // inclusive H-S scan of 392 counts (all 512 threads)
        sm.p.hs[tid] = (tid < BPH) ? sm.p.lcur[tid] : 0;
        __syncthreads();
        for (int o = 1; o < 512; o <<= 1) {
            int v = 0;
            if (tid >= o) v = sm.p.hs[tid - o];
            __syncthreads();
            sm.p.hs[tid] += v;
            __syncthreads();
        }
        if (tid < BPH) {
            sm.p.lstart[tid] = sm.p.hs[tid] - sm.p.lcur[tid];
            if (sm.p.lcur[tid] > 0) {
                const int g = atomicAdd(&bincur[h * BPH + tid], sm.p.lcur[tid]);
                sm.p.gdst[tid] = (h * BPH + tid) * CAP + g;
            }
        }
        __syncthreads();

        // reorder into LDS stage via saved rank
#pragma unroll
        for (int k = 0; k < EPT; ++k) {
            if (ent[k] != 0xffffffffu) {
                const int b = (int)((ent[k] & 0xffffu) >> GBITS);
                sm.p.stage[sm.p.lstart[b] + (int)rk[k]] = ent[k];
            }
        }
        __syncthreads();

        const int tot = sm.p.lstart[BPH - 1] + sm.p.lcur[BPH - 1];
        for (int i = tid; i < tot; i += TPB1) {
            const unsigned e = sm.p.stage[i];
            const int b = (int)((e & 0xffffu) >> GBITS);
            seg1[(size_t)sm.p.gdst[b] + (i - sm.p.lstart[b])] = e;
        }
    } else {
        // ------------------- transform role (persistent, W-in-regs) --------
        const int t    = L - NPB;
        const int h    = t & 3;
        const int part = t >> 2;             // 0..TPART-1
        const int c    = tid & 31;
        const int ng   = tid >> 5;           // 0..15 node sub-group

        // W column -> 64 VGPRs, once per block (coalesced per-k dword loads)
        float wlc[D], wrc[D];
#pragma unroll
        for (int k = 0; k < D; ++k) {
            wlc[k] = Wl[h * D * D + k * D + c];
            wrc[k] = Wr[h * D * D + k * D + c];
        }

        for (int nb = part; nb < NG64; nb += TPART) {
            __syncthreads();     // prior iteration's readers done
            const int base = nb * 64;
            const int nn   = (Nn - base) < 64 ? (Nn - base) : 64;
            const float4* xsrc = (const float4*)(x + ((size_t)h * Nn + base) * D);
            for (int i = tid; i < nn * 8; i += TPB1)
                ((float4*)sm.t.xs)[i] = xsrc[i];
            __syncthreads();

#pragma unroll
            for (int i = 0; i < 4; ++i) {
                const int nl = ng * 4 + i;       // local node 0..63
                if (nl < nn) {
                    const float4* xr4 = (const float4*)(sm.t.xs + nl * D);
                    float al = 0.f, ar = 0.f;
#pragma unroll
                    for (int kc = 0; kc < 8; ++kc) {
                        const float4 xv = xr4[kc];   // broadcast b128
                        al = fmaf(xv.x, wlc[4*kc+0], al); ar = fmaf(xv.x, wrc[4*kc+0], ar);
                        al = fmaf(xv.y, wlc[4*kc+1], al); ar = fmaf(xv.y, wrc[4*kc+1], ar);
                        al = fmaf(xv.z, wlc[4*kc+2], al); ar = fmaf(xv.z, wrc[4*kc+2], ar);
                        al = fmaf(xv.w, wlc[4*kc+3], al); ar = fmaf(xv.w, wrc[4*kc+3], ar);
                    }
                    const size_t o = ((size_t)h * Nn + base + nl) * D + c;
                    xlh[o] = (_Float16)al;
                    xrh[o] = (_Float16)ar;
                }
            }
        }
    }
}

// ---------------------------------------------------------------------------
// Pass 2 (fused rowsort + accum): one block per bin (128 nodes), 512 threads.
// R7: __launch_bounds__(512, 4) -- the R6 regression was the 64-VGPR cap of
//     (512,8) forcing scratch spill/fill of the staged ev[] AND the pipeline
//     registers inside the inner loop (FETCH 59->220MB, WRITE 41->192MB with
//     VGPR_Count pinned at the cap). 128-VGPR budget holds everything;
//     occupancy 2 blocks/CU is compensated by the 3-deep ILP pipeline.
// Phase A : SINGLE-PASS seg1: each thread stages its <=10 edges in registers
//           during the histogram, then scatters from registers (deletes the
//           26MB seg1 re-read). Row runs padded EVEN -> each 2-edge batch's
//           indices are one aligned ushort2 LDS broadcast read.
// Phase A': counting-sort row ids by DESCENDING degree -> wave's 16 lockstep
//           groups hold near-equal-degree rows.
// Phase B : 3-deep gather pipeline (A/B/C rotation + prefetched odd edge):
//           two proc-pairs (~240cy VALU) cover the ~200cy L2 gather latency.
//           Proc order per row unchanged -> numerics identical.
// ---------------------------------------------------------------------------
__global__ __launch_bounds__(512, 4)
void sortaccum_kernel(const int* __restrict__ bincur, const unsigned* __restrict__ seg1,
                      const _Float16* __restrict__ xlh, const _Float16* __restrict__ xrh,
                      const float* __restrict__ att, const float* __restrict__ bias,
                      float* __restrict__ out) {
    __shared__ int rcnt[GW];
    __shared__ int rcur[GW];
    __shared__ int rowbeg[GW];
    __shared__ int rowdeg[GW];
    __shared__ unsigned short s2[S2CAP];
    __shared__ unsigned short order[GW];

    const int tid = threadIdx.x;
    const int L   = blockIdx.x;                 // 1568 = 196 * 8
    const int xcd = L & 7;
    const int h   = xcd >> 1;
    const int b   = ((L >> 3) << 1) | (L & 1);  // 0..391
    const int nodebase = b * GW;
    if (nodebase >= Nn) return;                 // pad bin (b==391), block-uniform
    const int bin = h * BPH + b;
    const int nrows = (Nn - nodebase) < GW ? (Nn - nodebase) : GW;
    const int cnt   = bincur[bin];
    const size_t base = (size_t)bin * CAP;
    const int hbase = h * Nn;

    if (tid < GW) rcnt[tid] = 0;
    __syncthreads();

    // single pass over seg1: stage in registers + histogram
    unsigned ev[EPT2];
#pragma unroll
    for (int k = 0; k < EPT2; ++k) {
        const int i = tid + k * 512;
        if (i < cnt) {
            ev[k] = seg1[base + i];
            atomicAdd(&rcnt[ev[k] & (GW - 1)], 1);
        }
    }
    __syncthreads();

    // extract degree, pad runs to even length, H-S scan the padded counts
    int deg = 0, pad = 0;
    if (tid < GW) {
        deg = rcnt[tid];
        rowdeg[tid] = deg;
        pad = (deg + 1) & ~1;
        rcnt[tid] = pad;
    }
    __syncthreads();
    for (int o = 1; o < GW; o <<= 1) {
        int a = 0;
        if (tid < GW && tid >= o) a = rcnt[tid - o];
        __syncthreads();
        if (tid < GW) rcnt[tid] += a;
        __syncthreads();
    }
    if (tid < GW) {
        const int excl = rcnt[tid] - pad;       // even (scan of evens)
        rcur[tid]   = excl;
        rowbeg[tid] = excl;
    }
    __syncthreads();

    // scatter from registers (no second seg1 read)
#pragma unroll
    for (int k = 0; k < EPT2; ++k) {
        const int i = tid + k * 512;
        if (i < cnt) {
            const int p = atomicAdd(&rcur[ev[k] & (GW - 1)], 1);
            s2[p] = (unsigned short)(ev[k] >> 16);
        }
    }
    __syncthreads();

    // ---------- phase A': counting-sort rows by descending degree ----------
    if (tid < GW) rcnt[tid] = 0;
    __syncthreads();
    int key = 0;
    if (tid < nrows) {
        key = deg > (GW - 1) ? 0 : (GW - 1 - deg);  // big degrees first
        atomicAdd(&rcnt[key], 1);
    }
    __syncthreads();
    int kv = 0;
    if (tid < GW) kv = rcnt[tid];
    for (int o = 1; o < GW; o <<= 1) {
        int a = 0;
        if (tid < GW && tid >= o) a = rcnt[tid - o];
        __syncthreads();
        if (tid < GW) rcnt[tid] += a;
        __syncthreads();
    }
    if (tid < GW) rcur[tid] = rcnt[tid] - kv;       // exclusive starts
    __syncthreads();
    if (tid < nrows) {
        const int p = atomicAdd(&rcur[key], 1);
        order[p] = (unsigned short)tid;
    }
    __syncthreads();

    // ------------------- phase B: accumulate -------------------
    const int l4  = tid & 3;
    const int gid = tid >> 2;                   // 128 groups

    v2h a0, a1, a2, a3;
    {
        const float* ap = att + h * D + l4 * 8;
        a0[0] = (_Float16)ap[0]; a0[1] = (_Float16)ap[1];
        a1[0] = (_Float16)ap[2]; a1[1] = (_Float16)ap[3];
        a2[0] = (_Float16)ap[4]; a2[1] = (_Float16)ap[5];
        a3[0] = (_Float16)ap[6]; a3[1] = (_Float16)ap[7];
    }
    const v2h sl2 = {(_Float16)NEG_SLOPE, (_Float16)NEG_SLOPE};
    const float* bp = bias + h * D + l4 * 8;
    const _Float16* xlb = xlh + (size_t)hbase * D + l4 * 8;

    for (int q = gid; q < nrows; q += 128) {
        const int j = (int)order[q];

        const int n = nodebase + j;
        const int r = hbase + n;
        const int beg = rowbeg[j];
        const int dg  = rowdeg[j];
        const int nb  = dg >> 1;                // 2-edge batches

        U16B xr8; xr8.u = *(const uint4*)(xrh + (size_t)r * D + l4 * 8);

        float ac0 = 0.f, ac1 = 0.f, ac2 = 0.f, ac3 = 0.f;
        float ac4 = 0.f, ac5 = 0.f, ac6 = 0.f, ac7 = 0.f;
        float den = 0.f;

        auto proc = [&](const H8& xg) {
            const v2h h0 = xg.a + xr8.h.a, h1 = xg.b + xr8.h.b;
            const v2h h2 = xg.c + xr8.h.c, h3 = xg.d + xr8.h.d;
            const v2h l0 = __builtin_elementwise_max(h0, h0 * sl2);
            const v2h l1 = __builtin_elementwise_max(h1, h1 * sl2);
            const v2h l2 = __builtin_elementwise_max(h2, h2 * sl2);
            const v2h l3 = __builtin_elementwise_max(h3, h3 * sl2);
            float p;
#ifdef HAS_FDOT2
            p = __builtin_amdgcn_fdot2(l0, a0, 0.f, false);
            p = __builtin_amdgcn_fdot2(l1, a1, p, false);
            p = __builtin_amdgcn_fdot2(l2, a2, p, false);
            p = __builtin_amdgcn_fdot2(l3, a3, p, false);
#else
            p  = (float)l0[0] * (float)a0[0] + (float)l0[1] * (float)a0[1];
            p += (float)l1[0] * (float)a1[0] + (float)l1[1] * (float)a1[1];
            p += (float)l2[0] * (float)a2[0] + (float)l2[1] * (float)a2[1];
            p += (float)l3[0] * (float)a3[0] + (float)l3[1] * (float)a3[1];
#endif
            p += __shfl_xor(p, 1, 4);
            p += __shfl_xor(p, 2, 4);
            const float w = __expf(p);
            ac0 = fmaf(w, (float)xg.a[0], ac0);
            ac1 = fmaf(w, (float)xg.a[1], ac1);
            ac2 = fmaf(w, (float)xg.b[0], ac2);
            ac3 = fmaf(w, (float)xg.b[1], ac3);
            ac4 = fmaf(w, (float)xg.c[0], ac4);
            ac5 = fmaf(w, (float)xg.c[1], ac5);
            ac6 = fmaf(w, (float)xg.d[0], ac6);
            ac7 = fmaf(w, (float)xg.d[1], ac7);
            den += w;
        };

        // prologue: batches 0,1 and the odd edge prefetched; self-loop proc
        // hides their latency.
        U16B gA0, gA1, gB0, gB1, gC0, gC1, gD0;
        if (nb > 0) {
            const ushort2 v = *(const ushort2*)(s2 + beg);
            gA0.u = *(const uint4*)(xlb + (size_t)v.x * D);
            gA1.u = *(const uint4*)(xlb + (size_t)v.y * D);
        }
        if (nb > 1) {
            const ushort2 v = *(const ushort2*)(s2 + beg + 2);
            gB0.u = *(const uint4*)(xlb + (size_t)v.x * D);
            gB1.u = *(const uint4*)(xlb + (size_t)v.y * D);
        }
        if (dg & 1) {
            const int s = (int)s2[beg + dg - 1];
            gD0.u = *(const uint4*)(xlb + (size_t)s * D);
        }
        {
            U16B xs; xs.u = *(const uint4*)(xlh + (size_t)r * D + l4 * 8);
            proc(xs.h);
        }

        // steady state: rotate A->B->C; always 2 batches of proc between a
        // fetch and its consumption.
        int k = 0;
        for (; k + 3 <= nb; k += 3) {
            {
                const ushort2 v = *(const ushort2*)(s2 + beg + 2 * (k + 2));
                gC0.u = *(const uint4*)(xlb + (size_t)v.x * D);
                gC1.u = *(const uint4*)(xlb + (size_t)v.y * D);
            }
            proc(gA0.h);
            proc(gA1.h);
            if (k + 3 < nb) {
                const ushort2 v = *(const ushort2*)(s2 + beg + 2 * (k + 3));
                gA0.u = *(const uint4*)(xlb + (size_t)v.x * D);
                gA1.u = *(const uint4*)(xlb + (size_t)v.y * D);
            }
            proc(gB0.h);
            proc(gB1.h);
            if (k + 4 < nb) {
                const ushort2 v = *(const ushort2*)(s2 + beg + 2 * (k + 4));
                gB0.u = *(const uint4*)(xlb + (size_t)v.x * D);
                gB1.u = *(const uint4*)(xlb + (size_t)v.y * D);
            }
            proc(gC0.h);
            proc(gC1.h);
        }
        const int rem = nb - k;                 // 0, 1, or 2
        if (rem >= 1) { proc(gA0.h); proc(gA1.h); }
        if (rem >= 2) { proc(gB0.h); proc(gB1.h); }
        if (dg & 1)   { proc(gD0.h); }

        const float inv = 1.f / den;
        float* op = out + (size_t)n * (Hh * D) + h * D + l4 * 8;
        float4 o0, o1;
        o0.x = ac0 * inv + bp[0]; o0.y = ac1 * inv + bp[1];
        o0.z = ac2 * inv + bp[2]; o0.w = ac3 * inv + bp[3];
        o1.x = ac4 * inv + bp[4]; o1.y = ac5 * inv + bp[5];
        o1.z = ac6 * inv + bp[6]; o1.w = ac7 * inv + bp[7];
        ((float4*)op)[0] = o0;
        ((float4*)op)[1] = o1;
    }
}

extern "C" void kernel_launch(void* const* d_in, const int* in_sizes, int n_in,
                              void* d_out, int out_size, void* d_ws, size_t ws_size,
                              hipStream_t stream) {
    const float* x    = (const float*)d_in[0];
    const int*   ei   = (const int*)d_in[1];
    const float* Wl   = (const float*)d_in[2];
    const float* Wr   = (const float*)d_in[3];
    const float* att  = (const float*)d_in[4];
    const float* bias = (const float*)d_in[5];
    float* out = (float*)d_out;

    // workspace: xlh[6.4M f16] | xrh[6.4M f16] | seg1[1568*4864 u32 = 30.5MB] | bincur[1568]
    _Float16* xlh  = (_Float16*)d_ws;
    _Float16* xrh  = xlh + (size_t)Hh * Nn * D;
    unsigned* seg1 = (unsigned*)(xrh + (size_t)Hh * Nn * D);
    int*      bincur = (int*)(seg1 + (size_t)NBIN * CAP);

    hipMemsetAsync(bincur, 0, NBIN * sizeof(int), stream);

    pass1_kernel<<<NPB + NTB, TPB1, 0, stream>>>(x, Wl, Wr, ei, xlh, xrh, bincur, seg1);

    sortaccum_kernel<<<NBIN, 512, 0, stream>>>(bincur, seg1, xlh, xrh, att, bias, out);
}

// Round 8
// 197.097 us; speedup vs baseline: 1.3140x; 1.0363x over previous
//
#include <hip/hip_runtime.h>

#define NEG_SLOPE 0.2f

static constexpr int Hh   = 4;
static constexpr int Nn   = 50000;
static constexpr int Ee   = 1600000;
static constexpr int D    = 32;

static constexpr int GBITS = 7;                       // 128 nodes per bin
static constexpr int GW    = 1 << GBITS;
static constexpr int BPH   = 392;                     // 391 used + 1 pad (keeps NBIN % 8 == 0)
static constexpr int NBIN  = Hh * BPH;                // 1568 bins
static constexpr int CAP   = 4864;                    // mean 4096 + 12 sigma
static constexpr int S2CAP = CAP + GW;                // + <=1 pad slot per row
static constexpr int EPT2  = (CAP + 511) / 512;       // 10 staged edges/thread (pass 2)
static constexpr int T1    = 8192;                    // partition tile (edges)
static constexpr int TPB1  = 512;
static constexpr int EPT   = T1 / TPB1;               // 16 edges/thread
static constexpr int NPT   = (Ee + T1 - 1) / T1;      // 196 tiles/head
static constexpr int NPB   = NPT * Hh;                // 784 partition blocks
static constexpr int NG64  = (Nn + 63) / 64;          // 782 64-node groups/head
static constexpr int TPART = 250;                     // transform parts/head
static constexpr int NTB   = Hh * TPART;              // 1000 transform blocks

typedef _Float16 v2h __attribute__((ext_vector_type(2)));
struct H8 { v2h a, b, c, d; };                        // 8 halves = 16 B
union U16B { uint4 u; H8 h; };

#if defined(__has_builtin)
#if __has_builtin(__builtin_amdgcn_fdot2)
#define HAS_FDOT2 1
#endif
#endif

// quad-perm butterfly adds: v_add_f32_dpp replaces ds_swizzle+add pairs.
// quad_perm ctrl: [1,0,3,2] = 0xB1 (xor 1), [2,3,0,1] = 0x4E (xor 2).
__device__ __forceinline__ float dpp_xor1(float x) {
    union { float f; int i; } u, r;
    u.f = x;
    r.i = __builtin_amdgcn_mov_dpp(u.i, 0xB1, 0xF, 0xF, true);
    return r.f;
}
__device__ __forceinline__ float dpp_xor2(float x) {
    union { float f; int i; } u, r;
    u.f = x;
    r.i = __builtin_amdgcn_mov_dpp(u.i, 0x4E, 0xF, 0xF, true);
    return r.f;
}

// ---------------------------------------------------------------------------
// Pass 1: two roles in one launch (block-uniform branch).
//   blocks [0, NPB)        : LDS-staged radix partition of edges into 1568
//                            bins (R2 structure; direct global scatter (R3)
//                            caused L2 write-allocate amplification).
//   blocks [NPB, NPB+NTB)  : xl/xr = x @ W_{l,r} per head, stored f16.
//                            W column in registers (R5: was ~76us of LDS
//                            W re-reads; compiler does not hoist).
// ---------------------------------------------------------------------------
union SMem {
    struct {
        unsigned stage[T1];          // 32 KB
        int lcur[BPH];
        int lstart[BPH];
        int gdst[BPH];
        int hs[512];
    } p;
    struct {
        float xs[64 * D];            // 64 nodes x 32 floats (8 KB)
    } t;
};

__global__ __launch_bounds__(TPB1, 4)
void pass1_kernel(const float* __restrict__ x, const float* __restrict__ Wl,
                  const float* __restrict__ Wr, const int* __restrict__ ei,
                  _Float16* __restrict__ xlh, _Float16* __restrict__ xrh,
                  int* __restrict__ bincur, unsigned* __restrict__ seg1) {
    __shared__ SMem sm;
    const int L   = blockIdx.x;
    const int tid = threadIdx.x;

    if (L < NPB) {
        // ------------------- partition role -------------------
        const int h  = L & 3;
        const int tb = (L >> 2) * T1;

        for (int i = tid; i < BPH; i += TPB1) sm.p.lcur[i] = 0;
        __syncthreads();

        const int4* srcp = (const int4*)(ei + (size_t)h * 2 * Ee);
        const int4* dstp = (const int4*)(ei + (size_t)h * 2 * Ee + Ee);

        unsigned ent[EPT];
        unsigned short rk[EPT];
#pragma unroll
        for (int k = 0; k < EPT / 4; ++k) {
            const int e4 = tb + 4 * (k * TPB1 + tid);    // Ee % 4 == 0
            if (e4 < Ee) {
                const int4 s4 = srcp[e4 >> 2];
                const int4 d4 = dstp[e4 >> 2];
                ent[4 * k + 0] = ((unsigned)s4.x << 16) | (unsigned)d4.x;
                ent[4 * k + 1] = ((unsigned)s4.y << 16) | (unsigned)d4.y;
                ent[4 * k + 2] = ((unsigned)s4.z << 16) | (unsigned)d4.z;
                ent[4 * k + 3] = ((unsigned)s4.w << 16) | (unsigned)d4.w;
                rk[4 * k + 0] = (unsigned short)atomicAdd(&sm.p.lcur[d4.x >> GBITS], 1);
                rk[4 * k + 1] = (unsigned short)atomicAdd(&sm.p.lcur[d4.y >> GBITS], 1);
                rk[4 * k + 2] = (unsigned short)atomicAdd(&sm.p.lcur[d4.z >> GBITS], 1);
                rk[4 * k + 3] = (unsigned short)atomicAdd(&sm.p.lcur[d4.w >> GBITS], 1);
            } else {
                ent[4*k+0] = ent[4*k+1] = ent[4*k+2] = ent[4*k+3] = 0xffffffffu;
            }
        }
        __syncthreads();

        // inclusive H-S scan of 392 counts (all 512 threads)
        sm.p.hs[tid] = (tid < BPH) ? sm.p.lcur[tid] : 0;
        __syncthreads();
        for (int o = 1; o < 512; o <<= 1) {
            int v = 0;
            if (tid >= o) v = sm.p.hs[tid - o];
            __syncthreads();
            sm.p.hs[tid] += v;
            __syncthreads();
        }
        if (tid < BPH) {
            sm.p.lstart[tid] = sm.p.hs[tid] - sm.p.lcur[tid];
            if (sm.p.lcur[tid] > 0) {
                const int g = atomicAdd(&bincur[h * BPH + tid], sm.p.lcur[tid]);
                sm.p.gdst[tid] = (h * BPH + tid) * CAP + g;
            }
        }
        __syncthreads();

        // reorder into LDS stage via saved rank
#pragma unroll
        for (int k = 0; k < EPT; ++k) {
            if (ent[k] != 0xffffffffu) {
                const int b = (int)((ent[k] & 0xffffu) >> GBITS);
                sm.p.stage[sm.p.lstart[b] + (int)rk[k]] = ent[k];
            }
        }
        __syncthreads();

        const int tot = sm.p.lstart[BPH - 1] + sm.p.lcur[BPH - 1];
        for (int i = tid; i < tot; i += TPB1) {
            const unsigned e = sm.p.stage[i];
            const int b = (int)((e & 0xffffu) >> GBITS);
            seg1[(size_t)sm.p.gdst[b] + (i - sm.p.lstart[b])] = e;
        }
    } else {
        // ------------------- transform role (persistent, W-in-regs) --------
        const int t    = L - NPB;
        const int h    = t & 3;
        const int part = t >> 2;             // 0..TPART-1
        const int c    = tid & 31;
        const int ng   = tid >> 5;           // 0..15 node sub-group

        // W column -> 64 VGPRs, once per block (coalesced per-k dword loads)
        float wlc[D], wrc[D];
#pragma unroll
        for (int k = 0; k < D; ++k) {
            wlc[k] = Wl[h * D * D + k * D + c];
            wrc[k] = Wr[h * D * D + k * D + c];
        }

        for (int nb = part; nb < NG64; nb += TPART) {
            __syncthreads();     // prior iteration's readers done
            const int base = nb * 64;
            const int nn   = (Nn - base) < 64 ? (Nn - base) : 64;
            const float4* xsrc = (const float4*)(x + ((size_t)h * Nn + base) * D);
            for (int i = tid; i < nn * 8; i += TPB1)
                ((float4*)sm.t.xs)[i] = xsrc[i];
            __syncthreads();

#pragma unroll
            for (int i = 0; i < 4; ++i) {
                const int nl = ng * 4 + i;       // local node 0..63
                if (nl < nn) {
                    const float4* xr4 = (const float4*)(sm.t.xs + nl * D);
                    float al = 0.f, ar = 0.f;
#pragma unroll
                    for (int kc = 0; kc < 8; ++kc) {
                        const float4 xv = xr4[kc];   // broadcast b128
                        al = fmaf(xv.x, wlc[4*kc+0], al); ar = fmaf(xv.x, wrc[4*kc+0], ar);
                        al = fmaf(xv.y, wlc[4*kc+1], al); ar = fmaf(xv.y, wrc[4*kc+1], ar);
                        al = fmaf(xv.z, wlc[4*kc+2], al); ar = fmaf(xv.z, wrc[4*kc+2], ar);
                        al = fmaf(xv.w, wlc[4*kc+3], al); ar = fmaf(xv.w, wrc[4*kc+3], ar);
                    }
                    const size_t o = ((size_t)h * Nn + base + nl) * D + c;
                    xlh[o] = (_Float16)al;
                    xrh[o] = (_Float16)ar;
                }
            }
        }
    }
}

// ---------------------------------------------------------------------------
// Pass 2 (fused rowsort + accum): one block per bin (128 nodes), 512 threads.
// R8 (instruction-diet round; R5 vs R7 showed duration invariant to ILP/
//     occupancy at VALUBusy~52% -> cut issued instructions):
//   - quad_perm DPP adds replace the 2 shfl_xor DS ops per proc
//   - att pre-scaled by log2e -> exp2f (v_exp only, no v_mul)
//   - wave-0 __shfl_up scans replace the two 14-barrier H-S scans
//     (~34 -> ~9 barriers/block)
// Phase A : SINGLE-PASS seg1 (register-staged ev[]), runs padded EVEN so
//           each 2-edge batch is one aligned ushort2 LDS broadcast read.
// Phase A': counting-sort rows by DESCENDING degree.
// Phase B : 3-deep gather pipeline (A/B/C + odd-edge D prefetch).
// ---------------------------------------------------------------------------
__global__ __launch_bounds__(512)
void sortaccum_kernel(const int* __restrict__ bincur, const unsigned* __restrict__ seg1,
                      const _Float16* __restrict__ xlh, const _Float16* __restrict__ xrh,
                      const float* __restrict__ att, const float* __restrict__ bias,
                      float* __restrict__ out) {
    __shared__ int rcnt[GW];
    __shared__ int rcur[GW];
    __shared__ int rowbeg[GW];
    __shared__ int rowdeg[GW];
    __shared__ unsigned short s2[S2CAP];
    __shared__ unsigned short order[GW];

    const int tid = threadIdx.x;
    const int L   = blockIdx.x;                 // 1568 = 196 * 8
    const int xcd = L & 7;
    const int h   = xcd >> 1;
    const int b   = ((L >> 3) << 1) | (L & 1);  // 0..391
    const int nodebase = b * GW;
    if (nodebase >= Nn) return;                 // pad bin (b==391), block-uniform
    const int bin = h * BPH + b;
    const int nrows = (Nn - nodebase) < GW ? (Nn - nodebase) : GW;
    const int cnt   = bincur[bin];
    const size_t base = (size_t)bin * CAP;
    const int hbase = h * Nn;

    if (tid < GW) rcnt[tid] = 0;
    __syncthreads();

    // single pass over seg1: stage in registers + histogram
    unsigned ev[EPT2];
#pragma unroll
    for (int k = 0; k < EPT2; ++k) {
        const int i = tid + k * 512;
        if (i < cnt) {
            ev[k] = seg1[base + i];
            atomicAdd(&rcnt[ev[k] & (GW - 1)], 1);
        }
    }
    __syncthreads();

    if (tid < GW) rowdeg[tid] = rcnt[tid];
    __syncthreads();

    // wave-0 exclusive scan of EVEN-padded degrees (2 rows/lane, no barriers
    // inside; replaces the 14-barrier 128-wide H-S scan)
    if (tid < 64) {
        const int d0 = rowdeg[2 * tid], d1 = rowdeg[2 * tid + 1];
        const int p0 = (d0 + 1) & ~1, p1 = (d1 + 1) & ~1;
        const int s  = p0 + p1;
        int incl = s;
#pragma unroll
        for (int o = 1; o < 64; o <<= 1) {
            const int t = __shfl_up(incl, o);
            if (tid >= (unsigned)o) incl += t;
        }
        const int e0 = incl - s;
        rowbeg[2 * tid]     = e0;
        rowbeg[2 * tid + 1] = e0 + p0;
        rcur[2 * tid]       = e0;
        rcur[2 * tid + 1]   = e0 + p0;
    }
    __syncthreads();

    // scatter from registers (no second seg1 read)
#pragma unroll
    for (int k = 0; k < EPT2; ++k) {
        const int i = tid + k * 512;
        if (i < cnt) {
            const int p = atomicAdd(&rcur[ev[k] & (GW - 1)], 1);
            s2[p] = (unsigned short)(ev[k] >> 16);
        }
    }
    __syncthreads();

    // ---------- phase A': counting-sort rows by descending degree ----------
    if (tid < GW) rcnt[tid] = 0;
    __syncthreads();
    int key = 0;
    if (tid < nrows) {
        const int dgt = rowdeg[tid];
        key = dgt > (GW - 1) ? 0 : (GW - 1 - dgt);  // big degrees first
        atomicAdd(&rcnt[key], 1);
    }
    __syncthreads();
    if (tid < 64) {
        const int c0 = rcnt[2 * tid], c1 = rcnt[2 * tid + 1];
        const int s  = c0 + c1;
        int incl = s;
#pragma unroll
        for (int o = 1; o < 64; o <<= 1) {
            const int t = __shfl_up(incl, o);
            if (tid >= (unsigned)o) incl += t;
        }
        const int e0 = incl - s;
        rcur[2 * tid]     = e0;
        rcur[2 * tid + 1] = e0 + c0;
    }
    __syncthreads();
    if (tid < nrows) {
        const int p = atomicAdd(&rcur[key], 1);
        order[p] = (unsigned short)tid;
    }
    __syncthreads();

    // ------------------- phase B: accumulate -------------------
    const int l4  = tid & 3;
    const int gid = tid >> 2;                   // 128 groups

    // att pre-scaled by log2e: exp(p) == exp2(p_scaled) -> saves the v_mul
    // inside __expf for every edge.
    constexpr float LOG2E = 1.4426950408889634f;
    v2h a0, a1, a2, a3;
    {
        const float* ap = att + h * D + l4 * 8;
        a0[0] = (_Float16)(ap[0] * LOG2E); a0[1] = (_Float16)(ap[1] * LOG2E);
        a1[0] = (_Float16)(ap[2] * LOG2E); a1[1] = (_Float16)(ap[3] * LOG2E);
        a2[0] = (_Float16)(ap[4] * LOG2E); a2[1] = (_Float16)(ap[5] * LOG2E);
        a3[0] = (_Float16)(ap[6] * LOG2E); a3[1] = (_Float16)(ap[7] * LOG2E);
    }
    const v2h sl2 = {(_Float16)NEG_SLOPE, (_Float16)NEG_SLOPE};
    const float* bp = bias + h * D + l4 * 8;
    const _Float16* xlb = xlh + (size_t)hbase * D + l4 * 8;

    for (int q = gid; q < nrows; q += 128) {
        const int j = (int)order[q];

        const int n = nodebase + j;
        const int r = hbase + n;
        const int beg = rowbeg[j];
        const int dg  = rowdeg[j];
        const int nb  = dg >> 1;                // 2-edge batches

        U16B xr8; xr8.u = *(const uint4*)(xrh + (size_t)r * D + l4 * 8);

        float ac0 = 0.f, ac1 = 0.f, ac2 = 0.f, ac3 = 0.f;
        float ac4 = 0.f, ac5 = 0.f, ac6 = 0.f, ac7 = 0.f;
        float den = 0.f;

        auto proc = [&](const H8& xg) {
            const v2h h0 = xg.a + xr8.h.a, h1 = xg.b + xr8.h.b;
            const v2h h2 = xg.c + xr8.h.c, h3 = xg.d + xr8.h.d;
            const v2h l0 = __builtin_elementwise_max(h0, h0 * sl2);
            const v2h l1 = __builtin_elementwise_max(h1, h1 * sl2);
            const v2h l2 = __builtin_elementwise_max(h2, h2 * sl2);
            const v2h l3 = __builtin_elementwise_max(h3, h3 * sl2);
            float p;
#ifdef HAS_FDOT2
            p = __builtin_amdgcn_fdot2(l0, a0, 0.f, false);
            p = __builtin_amdgcn_fdot2(l1, a1, p, false);
            p = __builtin_amdgcn_fdot2(l2, a2, p, false);
            p = __builtin_amdgcn_fdot2(l3, a3, p, false);
#else
            p  = (float)l0[0] * (float)a0[0] + (float)l0[1] * (float)a0[1];
            p += (float)l1[0] * (float)a1[0] + (float)l1[1] * (float)a1[1];
            p += (float)l2[0] * (float)a2[0] + (float)l2[1] * (float)a2[1];
            p += (float)l3[0] * (float)a3[0] + (float)l3[1] * (float)a3[1];
#endif
            p += dpp_xor1(p);                   // v_add_f32_dpp quad xor1
            p += dpp_xor2(p);                   // v_add_f32_dpp quad xor2
            const float w = exp2f(p);           // att pre-scaled by log2e
            ac0 = fmaf(w, (float)xg.a[0], ac0);
            ac1 = fmaf(w, (float)xg.a[1], ac1);
            ac2 = fmaf(w, (float)xg.b[0], ac2);
            ac3 = fmaf(w, (float)xg.b[1], ac3);
            ac4 = fmaf(w, (float)xg.c[0], ac4);
            ac5 = fmaf(w, (float)xg.c[1], ac5);
            ac6 = fmaf(w, (float)xg.d[0], ac6);
            ac7 = fmaf(w, (float)xg.d[1], ac7);
            den += w;
        };

        // prologue: batches 0,1 and the odd edge prefetched; self-loop proc
        // hides their latency.
        U16B gA0, gA1, gB0, gB1, gC0, gC1, gD0;
        if (nb > 0) {
            const ushort2 v = *(const ushort2*)(s2 + beg);
            gA0.u = *(const uint4*)(xlb + (size_t)v.x * D);
            gA1.u = *(const uint4*)(xlb + (size_t)v.y * D);
        }
        if (nb > 1) {
            const ushort2 v = *(const ushort2*)(s2 + beg + 2);
            gB0.u = *(const uint4*)(xlb + (size_t)v.x * D);
            gB1.u = *(const uint4*)(xlb + (size_t)v.y * D);
        }
        if (dg & 1) {
            const int s = (int)s2[beg + dg - 1];
            gD0.u = *(const uint4*)(xlb + (size_t)s * D);
        }
        {
            U16B xs; xs.u = *(const uint4*)(xlh + (size_t)r * D + l4 * 8);
            proc(xs.h);
        }

        // steady state: rotate A->B->C; always 2 batches of proc between a
        // fetch and its consumption.
        int k = 0;
        for (; k + 3 <= nb; k += 3) {
            {
                const ushort2 v = *(const ushort2*)(s2 + beg + 2 * (k + 2));
                gC0.u = *(const uint4*)(xlb + (size_t)v.x * D);
                gC1.u = *(const uint4*)(xlb + (size_t)v.y * D);
            }
            proc(gA0.h);
            proc(gA1.h);
            if (k + 3 < nb) {
                const ushort2 v = *(const ushort2*)(s2 + beg + 2 * (k + 3));
                gA0.u = *(const uint4*)(xlb + (size_t)v.x * D);
                gA1.u = *(const uint4*)(xlb + (size_t)v.y * D);
            }
            proc(gB0.h);
            proc(gB1.h);
            if (k + 4 < nb) {
                const ushort2 v = *(const ushort2*)(s2 + beg + 2 * (k + 4));
                gB0.u = *(const uint4*)(xlb + (size_t)v.x * D);
                gB1.u = *(const uint4*)(xlb + (size_t)v.y * D);
            }
            proc(gC0.h);
            proc(gC1.h);
        }
        const int rem = nb - k;                 // 0, 1, or 2
        if (rem >= 1) { proc(gA0.h); proc(gA1.h); }
        if (rem >= 2) { proc(gB0.h); proc(gB1.h); }
        if (dg & 1)   { proc(gD0.h); }

        const float inv = 1.f / den;
        float* op = out + (size_t)n * (Hh * D) + h * D + l4 * 8;
        float4 o0, o1;
        o0.x = ac0 * inv + bp[0]; o0.y = ac1 * inv + bp[1];
        o0.z = ac2 * inv + bp[2]; o0.w = ac3 * inv + bp[3];
        o1.x = ac4 * inv + bp[4]; o1.y = ac5 * inv + bp[5];
        o1.z = ac6 * inv + bp[6]; o1.w = ac7 * inv + bp[7];
        ((float4*)op)[0] = o0;
        ((float4*)op)[1] = o1;
    }
}

extern "C" void kernel_launch(void* const* d_in, const int* in_sizes, int n_in,
                              void* d_out, int out_size, void* d_ws, size_t ws_size,
                              hipStream_t stream) {
    const float* x    = (const float*)d_in[0];
    const int*   ei   = (const int*)d_in[1];
    const float* Wl   = (const float*)d_in[2];
    const float* Wr   = (const float*)d_in[3];
    const float* att  = (const float*)d_in[4];
    const float* bias = (const float*)d_in[5];
    float* out = (float*)d_out;

    // workspace: xlh[6.4M f16] | xrh[6.4M f16] | seg1[1568*4864 u32 = 30.5MB] | bincur[1568]
    _Float16* xlh  = (_Float16*)d_ws;
    _Float16* xrh  = xlh + (size_t)Hh * Nn * D;
    unsigned* seg1 = (unsigned*)(xrh + (size_t)Hh * Nn * D);
    int*      bincur = (int*)(seg1 + (size_t)NBIN * CAP);

    hipMemsetAsync(bincur, 0, NBIN * sizeof(int), stream);

    pass1_kernel<<<NPB + NTB, TPB1, 0, stream>>>(x, Wl, Wr, ei, xlh, xrh, bincur, seg1);

    sortaccum_kernel<<<NBIN, 512, 0, stream>>>(bincur, seg1, xlh, xrh, att, bias, out);
}